// Round 10
// baseline (104.870 us; speedup 1.0000x reference)
//
#include <hip/hip_runtime.h>

typedef __attribute__((ext_vector_type(4))) float f32x4;
typedef __attribute__((ext_vector_type(8))) short s16x8;

#define NG     8000
#define NRPT   8000
#define NSKIN  128
#define NT     32          // r-cols per block
#define KK     32
#define KCH    800
#define NKC    10
#define NTILES 25
#define NTOT   (NKC*NTILES)   // 250 K-tiles
#define TPB    256
#define WS_TILE_B 24576    // per K-tile: Ar|Ai|Asum planes, 8KB each, pre-swizzled
#define WS_NEED   ((size_t)NTOT*WS_TILE_B)   // 6,144,000 B

// LDS byte offsets
#define S_AR 0
#define S_AI 8192
#define S_AS 16384
#define S_BC 24576
#define S_BS 26624
#define S_BU 28672
#define S_SZ 30720

__device__ __forceinline__ float sin_rev(float u){ float r; asm("v_sin_f32 %0, %1" : "=v"(r) : "v"(u)); return r; }
__device__ __forceinline__ float cos_rev(float u){ float r; asm("v_cos_f32 %0, %1" : "=v"(r) : "v"(u)); return r; }
__device__ __forceinline__ unsigned int cvt_pk(float lo, float hi){
    unsigned int r; asm("v_cvt_pk_bf16_f32 %0, %1, %2" : "=v"(r) : "v"(lo), "v"(hi)); return r;
}
// swizzled byte offset of 16B granule (row,kg) in a [rows][32]-ushort tile (64B rows).
// kg' = kg ^ ((row>>1)&3): b128 stage-writes and b128 frag reads both land
// 8 lanes per 16B bank-group -> conflict-free. Invariant under row+16 (+1024B).
__device__ __forceinline__ int swz(int row, int kg){
    return row*64 + ((kg ^ ((row>>1)&3))<<4);
}
__device__ __forceinline__ void glds16(const void* g, void* l){
    __builtin_amdgcn_global_load_lds((const __attribute__((address_space(1))) void*)g,
                                     (__attribute__((address_space(3))) void*)l, 16, 0, 0);
}

// ---- pre-pass: cg fp32 -> bf16 {Ar, Ai, Ar+Ai} in pre-swizzled K-tile order ----
// gid (16B granule) = (tileIdx*3 + plane)*512 + row*4 + slot
// content = plane of cg[row][tileIdx*32 + kg*8 ..+8], kg = slot ^ ((row>>1)&3)
__global__ __launch_bounds__(256) void bloch_prepass(
    const float* __restrict__ cgr, const float* __restrict__ cgi,
    char* __restrict__ ws)
{
    int gid = blockIdx.x*256 + threadIdx.x;
    if (gid >= NTOT*3*512) return;
    int slot  = gid & 3;
    int row   = (gid >> 2) & 127;
    int pt    = gid >> 9;
    int tileIdx = pt / 3;
    int plane   = pt - tileIdx*3;
    int kg = slot ^ ((row >> 1) & 3);
    int k  = tileIdx*KK + kg*8;     // chunks are K-contiguous: kc*800+t*32 = tileIdx*32
    uint4 p;
    if (plane == 0 || plane == 1) {
        const float* src = plane ? cgi : cgr;
        const float4 v0 = *(const float4*)&src[(size_t)row*NG + k];
        const float4 v1 = *(const float4*)&src[(size_t)row*NG + k + 4];
        p.x = cvt_pk(v0.x, v0.y); p.y = cvt_pk(v0.z, v0.w);
        p.z = cvt_pk(v1.x, v1.y); p.w = cvt_pk(v1.z, v1.w);
    } else {
        const float4 r0 = *(const float4*)&cgr[(size_t)row*NG + k];
        const float4 r1 = *(const float4*)&cgr[(size_t)row*NG + k + 4];
        const float4 i0 = *(const float4*)&cgi[(size_t)row*NG + k];
        const float4 i1 = *(const float4*)&cgi[(size_t)row*NG + k + 4];
        p.x = cvt_pk(r0.x+i0.x, r0.y+i0.y); p.y = cvt_pk(r0.z+i0.z, r0.w+i0.w);
        p.z = cvt_pk(r1.x+i1.x, r1.y+i1.y); p.w = cvt_pk(r1.z+i1.z, r1.w+i1.w);
    }
    *(uint4*)(ws + (size_t)gid*16) = p;
}

// (256,4): 4 waves/EU, total reg cap 128/wave. Karatsuba acc = 48 + ~55 arch fits.
// (R8 lesson: (256,6) capped at ~85 -> acc spilled, 1.5GB scratch traffic.)
template<bool PRE>
__global__ __launch_bounds__(TPB, 4) void bloch9(
    const float* __restrict__ Amat, const float* __restrict__ kgrid,
    const float* __restrict__ cgr,  const float* __restrict__ cgi,
    const float* __restrict__ rpts, const char* __restrict__ ws,
    float* __restrict__ out, int out_size)
{
    __shared__ __align__(16) char smem[S_SZ];   // A 24K | B 6K; ekr overlay after loop
    __shared__ float fracS[NT][4];
    __shared__ float invAS[9];
    __shared__ float scaleS;

    const int tid = threadIdx.x;
    const int bid = blockIdx.x;
    // kc-partners of an output tile are 256 apart in bid -> same bid%8 -> same XCD
    const int kc  = bid >> 8;           // 0..9
    const int rb  = bid & 255;          // 0..255
    if (rb >= 250) return;              // uniform early-out
    const int r_base  = rb * NT;
    const int k_begin = kc * KCH;

    if (tid == 0) {
        float a00=Amat[0],a01=Amat[1],a02=Amat[2];
        float a10=Amat[3],a11=Amat[4],a12=Amat[5];
        float a20=Amat[6],a21=Amat[7],a22=Amat[8];
        float c00 =  (a11*a22 - a12*a21);
        float c01 = -(a10*a22 - a12*a20);
        float c02 =  (a10*a21 - a11*a20);
        float det = a00*c00 + a01*c01 + a02*c02;
        float id  = 1.0f/det;
        invAS[0] =  c00*id;
        invAS[1] = -(a01*a22 - a02*a21)*id;
        invAS[2] =  (a01*a12 - a02*a11)*id;
        invAS[3] =  c01*id;
        invAS[4] =  (a00*a22 - a02*a20)*id;
        invAS[5] = -(a00*a12 - a02*a10)*id;
        invAS[6] =  c02*id;
        invAS[7] = -(a00*a21 - a01*a20)*id;
        invAS[8] =  (a00*a11 - a01*a10)*id;
        scaleS   = rsqrtf(fabsf(det));
    }
    __syncthreads();

    if (tid < NT) {
        int rg = r_base + tid;
        float r0 = rpts[rg*3+0], r1 = rpts[rg*3+1], r2 = rpts[rg*3+2];
        fracS[tid][0] = r0*invAS[0] + r1*invAS[3] + r2*invAS[6];
        fracS[tid][1] = r0*invAS[1] + r1*invAS[4] + r2*invAS[7];
        fracS[tid][2] = r0*invAS[2] + r1*invAS[5] + r2*invAS[8];
    }
    __syncthreads();

    f32x4 accP1[4], accP2[4], accP3[4];
    #pragma unroll
    for (int mi = 0; mi < 4; ++mi) {
        accP1[mi] = (f32x4){0.f,0.f,0.f,0.f};
        accP2[mi] = (f32x4){0.f,0.f,0.f,0.f};
        accP3[mi] = (f32x4){0.f,0.f,0.f,0.f};
    }

    const int lane = tid & 63;
    const int wid  = tid >> 6;     // 0..3
    const int wm   = wid >> 1;     // 0..1 (M half: 64 rows)
    const int wn   = wid & 1;      // 0..1 (N half: 16 cols)
    const int frow = lane & 15;
    const int kq   = lane >> 4;

    const int aOff = swz(wm*64 + frow, kq);
    const int bOff = swz(wn*16 + frow, kq);

    // B staging handled by waves 0-1 (tid<128): row sB=tid>>2 in 0..31
    const int sB  = tid >> 2;
    const int qtr = tid & 3;
    const int stOffB = swz(sB & 31, qtr);

    float f0r=0.f, f1r=0.f, f2r=0.f;
    float w1c=0.f, w1s=0.f, w1wdc=0.f, w1wds=0.f;
    if (tid < 128) {
        f0r = fracS[sB][0]; f1r = fracS[sB][1]; f2r = fracS[sB][2];
        float u1 = f2r - floorf(f2r);
        w1c = cos_rev(u1); w1s = sin_rev(u1);
        float yd = -20.0f * f2r; yd -= floorf(yd);
        float wdc = cos_rev(yd), wds = sin_rev(yd);
        w1wdc = w1c*wdc - w1s*wds;
        w1wds = w1c*wds + w1s*wdc;
    }

    #pragma unroll 1
    for (int t = 0; t < NTILES; ++t) {
        const int kb = k_begin + t*KK;

        // ---- stage A: 3 planes ----
        if (PRE) {
            const char* tb = ws + (size_t)(kc*NTILES + t)*WS_TILE_B;
            glds16(tb +          tid*16, smem + S_AR +        tid*16);
            glds16(tb + 4096  +  tid*16, smem + S_AR + 4096 + tid*16);
            glds16(tb + 8192  +  tid*16, smem + S_AI +        tid*16);
            glds16(tb + 12288 +  tid*16, smem + S_AI + 4096 + tid*16);
            glds16(tb + 16384 +  tid*16, smem + S_AS +        tid*16);
            glds16(tb + 20480 +  tid*16, smem + S_AS + 4096 + tid*16);
        } else {
            #pragma unroll
            for (int j = 0; j < 2; ++j) {
                int row = (tid>>2) + 64*j;
                int kg  = qtr ^ ((row>>1)&3);
                int k   = kb + kg*8;
                const float4 v0r = *(const float4*)&cgr[(size_t)row*NG + k];
                const float4 v1r = *(const float4*)&cgr[(size_t)row*NG + k + 4];
                const float4 v0i = *(const float4*)&cgi[(size_t)row*NG + k];
                const float4 v1i = *(const float4*)&cgi[(size_t)row*NG + k + 4];
                uint4 pr, pi, ps;
                pr.x = cvt_pk(v0r.x, v0r.y); pr.y = cvt_pk(v0r.z, v0r.w);
                pr.z = cvt_pk(v1r.x, v1r.y); pr.w = cvt_pk(v1r.z, v1r.w);
                pi.x = cvt_pk(v0i.x, v0i.y); pi.y = cvt_pk(v0i.z, v0i.w);
                pi.z = cvt_pk(v1i.x, v1i.y); pi.w = cvt_pk(v1i.z, v1i.w);
                ps.x = cvt_pk(v0r.x+v0i.x, v0r.y+v0i.y); ps.y = cvt_pk(v0r.z+v0i.z, v0r.w+v0i.w);
                ps.z = cvt_pk(v1r.x+v1i.x, v1r.y+v1i.y); ps.w = cvt_pk(v1r.z+v1i.z, v1r.w+v1i.w);
                *(uint4*)(smem + S_AR + row*64 + qtr*16) = pr;
                *(uint4*)(smem + S_AI + row*64 + qtr*16) = pi;
                *(uint4*)(smem + S_AS + row*64 + qtr*16) = ps;
            }
        }

        // ---- stage B (waves 0-1): 8-phase complex recurrence + Bsum ----
        if (tid < 128) {
            int g0   = kb + qtr*8;
            int i12  = (g0 * 3277) >> 16;            // g0/20 (exact, g0<16000)
            int i3_0 = g0 - i12*20;
            int i1a  = (i12 * 3277) >> 16; int i2a = i12 - i1a*20;
            int i12b = i12 + 1;
            int i1b  = (i12b * 3277) >> 16; int i2b = i12b - i1b*20;
            float m1a = (float)(i1a - (i1a >= 10 ? 20 : 0));
            float m2a = (float)(i2a - (i2a >= 10 ? 20 : 0));
            float m1b = (float)(i1b - (i1b >= 10 ? 20 : 0));
            float m2b = (float)(i2b - (i2b >= 10 ? 20 : 0));
            float m30 = (float)(i3_0 - (i3_0 >= 10 ? 20 : 0));
            float y0 = m1a*f0r + m2a*f1r + m30*f2r; y0 -= floorf(y0);
            float cc = cos_rev(y0), cs = sin_rev(y0);
            float rd = (m1b-m1a)*f0r + (m2b-m2a)*f1r; rd -= floorf(rd);
            float rc = cos_rev(rd), rs = sin_rev(rd);
            float wXc = w1c*rc - w1s*rs;
            float wXs = w1c*rs + w1s*rc;
            float bcv[8], bsv[8];
            bcv[0] = cc; bsv[0] = cs;
            #pragma unroll
            for (int j = 1; j < 8; ++j) {
                bool cB = (i3_0 == 20 - j);
                bool cD = (i3_0 == 10 - j);
                float mc = cB ? wXc : (cD ? w1wdc : w1c);
                float ms = cB ? wXs : (cD ? w1wds : w1s);
                float nc = cc*mc - cs*ms;
                float ns = cc*ms + cs*mc;
                cc = nc; cs = ns;
                bcv[j] = cc; bsv[j] = cs;
            }
            uint4 wc, wsn, wu;
            wc.x  = cvt_pk(bcv[0], bcv[1]); wc.y  = cvt_pk(bcv[2], bcv[3]);
            wc.z  = cvt_pk(bcv[4], bcv[5]); wc.w  = cvt_pk(bcv[6], bcv[7]);
            wsn.x = cvt_pk(bsv[0], bsv[1]); wsn.y = cvt_pk(bsv[2], bsv[3]);
            wsn.z = cvt_pk(bsv[4], bsv[5]); wsn.w = cvt_pk(bsv[6], bsv[7]);
            wu.x  = cvt_pk(bcv[0]+bsv[0], bcv[1]+bsv[1]);
            wu.y  = cvt_pk(bcv[2]+bsv[2], bcv[3]+bsv[3]);
            wu.z  = cvt_pk(bcv[4]+bsv[4], bcv[5]+bsv[5]);
            wu.w  = cvt_pk(bcv[6]+bsv[6], bcv[7]+bsv[7]);
            *(uint4*)(smem + S_BC + stOffB) = wc;
            *(uint4*)(smem + S_BS + stOffB) = wsn;
            *(uint4*)(smem + S_BU + stOffB) = wu;
        }
        __syncthreads();   // RAW (drains glds vmcnt too)

        // ---- consume: 3 Karatsuba passes, wave tile 64m x 16n ----
        __builtin_amdgcn_s_setprio(1);
        {
            s16x8 b = *(const s16x8*)(smem + S_BC + bOff);
            #pragma unroll
            for (int mi = 0; mi < 4; ++mi) {
                s16x8 a = *(const s16x8*)(smem + S_AR + aOff + mi*1024);
                accP1[mi] = __builtin_amdgcn_mfma_f32_16x16x32_bf16(a, b, accP1[mi], 0, 0, 0);
            }
        }
        {
            s16x8 b = *(const s16x8*)(smem + S_BS + bOff);
            #pragma unroll
            for (int mi = 0; mi < 4; ++mi) {
                s16x8 a = *(const s16x8*)(smem + S_AI + aOff + mi*1024);
                accP2[mi] = __builtin_amdgcn_mfma_f32_16x16x32_bf16(a, b, accP2[mi], 0, 0, 0);
            }
        }
        {
            s16x8 b = *(const s16x8*)(smem + S_BU + bOff);
            #pragma unroll
            for (int mi = 0; mi < 4; ++mi) {
                s16x8 a = *(const s16x8*)(smem + S_AS + aOff + mi*1024);
                accP3[mi] = __builtin_amdgcn_mfma_f32_16x16x32_bf16(a, b, accP3[mi], 0, 0, 0);
            }
        }
        __builtin_amdgcn_s_setprio(0);
        __syncthreads();   // WAR
    }

    // ---- e^{i k.r} table overlay; one sincos per thread (tid<128) ----
    float2* ekr = (float2*)smem;   // [32][4]
    if (tid < 128) {
        int col = tid >> 2, kidx = tid & 3;
        int rg = r_base + col;
        float r0 = rpts[rg*3+0], r1 = rpts[rg*3+1], r2 = rpts[rg*3+2];
        float ang = (r0*kgrid[kidx*3+0] + r1*kgrid[kidx*3+1] + r2*kgrid[kidx*3+2])
                    * 0.15915494309189535f;
        float u = ang - floorf(ang);
        ekr[col*4+kidx] = make_float2(cos_rev(u), sin_rev(u));
    }
    __syncthreads();

    // ---- epilogue: Re = P1-P2, Im = P3-P1-P2; rotate, scale, atomic ----
    const bool write_imag = (out_size >= 2*NSKIN*NRPT);
    const float scale = scaleS;
    const int col = wn*16 + frow;
    const int rg  = r_base + col;
    #pragma unroll
    for (int mi = 0; mi < 4; ++mi) {
        const int m0 = wm*64 + mi*16;
        float2 e = ekr[col*4 + mi];      // kidx = (m0>>4)&3 == mi
        float ck = e.x, sk = e.y;
        #pragma unroll
        for (int v = 0; v < 4; ++v) {
            int sg = m0 + kq*4 + v;
            float p1 = accP1[mi][v], p2 = accP2[mi][v], p3 = accP3[mi][v];
            float re = p1 - p2;
            float im = p3 - p1 - p2;
            float orr = (re*ck - im*sk) * scale;
            size_t lin = (size_t)sg * NRPT + rg;
            if (write_imag) {
                float oi = (re*sk + im*ck) * scale;
                size_t idx = lin * 2;
                if (idx + 1 < (size_t)out_size) {
                    atomicAdd(&out[idx],   orr);
                    atomicAdd(&out[idx+1], oi);
                }
            } else {
                atomicAdd(&out[lin], orr);
            }
        }
    }
}

extern "C" void kernel_launch(void* const* d_in, const int* in_sizes, int n_in,
                              void* d_out, int out_size, void* d_ws, size_t ws_size,
                              hipStream_t stream) {
    const float* Amat  = (const float*)d_in[0];
    const float* kgrid = (const float*)d_in[1];
    const float* cgr   = (const float*)d_in[2];
    const float* cgi   = (const float*)d_in[3];
    const float* rpts  = (const float*)d_in[4];
    float* out = (float*)d_out;

    hipMemsetAsync(d_out, 0, (size_t)out_size * sizeof(float), stream);

    const bool use_pre = (ws_size >= WS_NEED);
    dim3 grid(NKC * 256);   // kc = bid>>8, rb = bid&255 (6 dead bids per kc)
    if (use_pre) {
        bloch_prepass<<<dim3(NTOT*3*512/256), 256, 0, stream>>>(cgr, cgi, (char*)d_ws);
        bloch9<true><<<grid, TPB, 0, stream>>>(Amat, kgrid, cgr, cgi, rpts,
                                               (const char*)d_ws, out, out_size);
    } else {
        bloch9<false><<<grid, TPB, 0, stream>>>(Amat, kgrid, cgr, cgi, rpts,
                                                nullptr, out, out_size);
    }
}

// Round 11
// 90.615 us; speedup vs baseline: 1.1573x; 1.1573x over previous
//
#include <hip/hip_runtime.h>

typedef __attribute__((ext_vector_type(4))) float f32x4;
typedef __attribute__((ext_vector_type(8))) short s16x8;

#define NG     8000
#define NRPT   8000
#define NSKIN  128
#define NT     64          // r-cols per block
#define KK     32
#define KCH    800
#define NKC    10
#define NTILES 25
#define NTOT   (NKC*NTILES)   // 250 K-tiles
#define TPB    256
#define WS_TILE_B 16384    // per K-tile: Ar|Ai planes, 8KB each, fragment-ordered
#define WS_NEED   ((size_t)NTOT*WS_TILE_B)   // 4,096,000 B

__device__ __forceinline__ float sin_rev(float u){ float r; asm("v_sin_f32 %0, %1" : "=v"(r) : "v"(u)); return r; }
__device__ __forceinline__ float cos_rev(float u){ float r; asm("v_cos_f32 %0, %1" : "=v"(r) : "v"(u)); return r; }
__device__ __forceinline__ unsigned int cvt_pk(float lo, float hi){
    unsigned int r; asm("v_cvt_pk_bf16_f32 %0, %1, %2" : "=v"(r) : "v"(lo), "v"(hi)); return r;
}
__device__ __forceinline__ s16x8 bneg(s16x8 v){
    int4 u = *(int4*)&v;
    u.x ^= 0x80008000; u.y ^= 0x80008000; u.z ^= 0x80008000; u.w ^= 0x80008000;
    return *(s16x8*)&u;
}
__device__ __forceinline__ s16x8 pack8(float4 v0, float4 v1){
    union { s16x8 v; uint4 u; } r;
    r.u.x = cvt_pk(v0.x,v0.y); r.u.y = cvt_pk(v0.z,v0.w);
    r.u.z = cvt_pk(v1.x,v1.y); r.u.w = cvt_pk(v1.z,v1.w);
    return r.v;
}
// swizzled byte offset of 16B granule (row,kg) in a [64][32]-ushort LDS tile (64B rows).
// kg' = kg ^ ((row>>1)&3): b128 stage-writes (sB=tid>>2,qtr=tid&3) and b128 frag
// reads (rows base+frow, kg=lane>>4) both land 8 lanes/bank-group -> conflict-free.
// xor term depends only on row bits [2:1] -> invariant under row+16 (+1024B).
__device__ __forceinline__ int swz(int row, int kg){
    return row*64 + ((kg ^ ((row>>1)&3))<<4);
}

// ---- pre-pass: cg fp32 -> bf16 in MFMA-fragment order ----
// 16B chunk gid = ((tile*2+plane)*8 + rb8)*64 + lane
// content = bf16(cg[rb8*16 + (lane&15)][tile*32 + (lane>>4)*8 .. +8])
// -> main kernel reads 1KB fully-coalesced per (plane,rowblock) per wave.
__global__ __launch_bounds__(256) void bloch_prepass(
    const float* __restrict__ cgr, const float* __restrict__ cgi,
    char* __restrict__ ws)
{
    int gid = blockIdx.x*256 + threadIdx.x;
    if (gid >= NTOT*2*8*64) return;
    int lane  = gid & 63;
    int rb8   = (gid >> 6) & 7;
    int plane = (gid >> 9) & 1;
    int tile  = gid >> 10;
    int row   = rb8*16 + (lane & 15);
    int k     = tile*KK + (lane >> 4)*8;
    const float* src = plane ? cgi : cgr;
    const float4 v0 = *(const float4*)&src[(size_t)row*NG + k];
    const float4 v1 = *(const float4*)&src[(size_t)row*NG + k + 4];
    uint4 p;
    p.x = cvt_pk(v0.x, v0.y); p.y = cvt_pk(v0.z, v0.w);
    p.z = cvt_pk(v1.x, v1.y); p.w = cvt_pk(v1.z, v1.w);
    *(uint4*)(ws + (size_t)gid*16) = p;
}

// (256,3): 3 waves/EU -> VGPR cap ~170. Live set ~140 (64 acc + 32 A-frag +
// 24 B-frag + temps) -> no spill. (R8 lesson: tighter caps spill the acc.)
template<bool PRE>
__global__ __launch_bounds__(TPB, 3) void bloch10(
    const float* __restrict__ Amat, const float* __restrict__ kgrid,
    const float* __restrict__ cgr,  const float* __restrict__ cgi,
    const float* __restrict__ rpts, const char* __restrict__ ws,
    float* __restrict__ out, int out_size)
{
    __shared__ __align__(16) char smemB[2*8192];   // per buf: Bc 4K | Bs 4K
    __shared__ float fracS[NT][4];
    __shared__ float invAS[9];
    __shared__ float scaleS;

    const int tid = threadIdx.x;
    const int bid = blockIdx.x;
    // kc-partners of an output tile are 128 apart in bid -> same bid%8 -> same XCD
    const int kc  = bid >> 7;           // 0..9
    const int rb  = bid & 127;          // 0..127
    if (rb >= 125) return;              // uniform early-out
    const int r_base  = rb * NT;
    const int k_begin = kc * KCH;

    if (tid == 0) {
        float a00=Amat[0],a01=Amat[1],a02=Amat[2];
        float a10=Amat[3],a11=Amat[4],a12=Amat[5];
        float a20=Amat[6],a21=Amat[7],a22=Amat[8];
        float c00 =  (a11*a22 - a12*a21);
        float c01 = -(a10*a22 - a12*a20);
        float c02 =  (a10*a21 - a11*a20);
        float det = a00*c00 + a01*c01 + a02*c02;
        float id  = 1.0f/det;
        invAS[0] =  c00*id;
        invAS[1] = -(a01*a22 - a02*a21)*id;
        invAS[2] =  (a01*a12 - a02*a11)*id;
        invAS[3] =  c01*id;
        invAS[4] =  (a00*a22 - a02*a20)*id;
        invAS[5] = -(a00*a12 - a02*a10)*id;
        invAS[6] =  c02*id;
        invAS[7] = -(a00*a21 - a01*a20)*id;
        invAS[8] =  (a00*a11 - a01*a10)*id;
        scaleS   = rsqrtf(fabsf(det));
    }
    __syncthreads();

    if (tid < NT) {
        int rg = r_base + tid;
        float r0 = rpts[rg*3+0], r1 = rpts[rg*3+1], r2 = rpts[rg*3+2];
        fracS[tid][0] = r0*invAS[0] + r1*invAS[3] + r2*invAS[6];
        fracS[tid][1] = r0*invAS[1] + r1*invAS[4] + r2*invAS[7];
        fracS[tid][2] = r0*invAS[2] + r1*invAS[5] + r2*invAS[8];
    }
    __syncthreads();

    f32x4 accRe[4][2], accIm[4][2];
    #pragma unroll
    for (int mi = 0; mi < 4; ++mi)
        #pragma unroll
        for (int ni = 0; ni < 2; ++ni) {
            accRe[mi][ni] = (f32x4){0.f,0.f,0.f,0.f};
            accIm[mi][ni] = (f32x4){0.f,0.f,0.f,0.f};
        }

    const int lane = tid & 63;
    const int wid  = tid >> 6;     // 0..3
    const int wm   = wid >> 1;     // 0..1 (M half: 64 rows)
    const int wn   = wid & 1;      // 0..1 (N half: 32 cols)
    const int frow = lane & 15;
    const int kq   = lane >> 4;

    const int sB   = tid >> 2;     // B stage row 0..63
    const int qtr  = tid & 3;      // k granule 0..3
    const int stOffB = swz(sB, qtr);
    const int bOff   = swz(wn*32 + frow, kq);

    const float f0r = fracS[sB][0], f1r = fracS[sB][1], f2r = fracS[sB][2];

    // recurrence constants: w1 = e^{2pi i f2}, w1wd = w1*e^{-2pi i 20 f2}
    float u1 = f2r - floorf(f2r);
    const float w1c = cos_rev(u1), w1s = sin_rev(u1);
    float yd = -20.0f * f2r; yd -= floorf(yd);
    const float wdc = cos_rev(yd), wds = sin_rev(yd);
    const float w1wdc = w1c*wdc - w1s*wds;
    const float w1wds = w1c*wds + w1s*wdc;

    auto stageB = [&](int kb, char* wb){
        int g0   = kb + qtr*8;
        int i12  = (g0 * 3277) >> 16;            // g0/20 (exact, g0<16000)
        int i3_0 = g0 - i12*20;
        int i1a  = (i12 * 3277) >> 16; int i2a = i12 - i1a*20;
        int i12b = i12 + 1;
        int i1b  = (i12b * 3277) >> 16; int i2b = i12b - i1b*20;
        float m1a = (float)(i1a - (i1a >= 10 ? 20 : 0));
        float m2a = (float)(i2a - (i2a >= 10 ? 20 : 0));
        float m1b = (float)(i1b - (i1b >= 10 ? 20 : 0));
        float m2b = (float)(i2b - (i2b >= 10 ? 20 : 0));
        float m30 = (float)(i3_0 - (i3_0 >= 10 ? 20 : 0));
        float y0 = m1a*f0r + m2a*f1r + m30*f2r; y0 -= floorf(y0);
        float cc = cos_rev(y0), cs = sin_rev(y0);
        float rd = (m1b-m1a)*f0r + (m2b-m2a)*f1r; rd -= floorf(rd);
        float rc = cos_rev(rd), rs = sin_rev(rd);
        float wXc = w1c*rc - w1s*rs;
        float wXs = w1c*rs + w1s*rc;
        float bcv[8], bsv[8];
        bcv[0] = cc; bsv[0] = cs;
        #pragma unroll
        for (int j = 1; j < 8; ++j) {
            bool cB = (i3_0 == 20 - j);   // i12 boundary
            bool cD = (i3_0 == 10 - j);   // m3 decade jump
            float mc = cB ? wXc : (cD ? w1wdc : w1c);
            float ms = cB ? wXs : (cD ? w1wds : w1s);
            float nc = cc*mc - cs*ms;
            float ns = cc*ms + cs*mc;
            cc = nc; cs = ns;
            bcv[j] = cc; bsv[j] = cs;
        }
        uint4 wc, wsn;
        wc.x  = cvt_pk(bcv[0], bcv[1]); wc.y  = cvt_pk(bcv[2], bcv[3]);
        wc.z  = cvt_pk(bcv[4], bcv[5]); wc.w  = cvt_pk(bcv[6], bcv[7]);
        wsn.x = cvt_pk(bsv[0], bsv[1]); wsn.y = cvt_pk(bsv[2], bsv[3]);
        wsn.z = cvt_pk(bsv[4], bsv[5]); wsn.w = cvt_pk(bsv[6], bsv[7]);
        *(uint4*)(wb +        stOffB) = wc;    // Bc plane
        *(uint4*)(wb + 4096 + stOffB) = wsn;   // Bs plane
    };

    // prologue: stage B(0) into buf0
    stageB(k_begin, smemB);
    __syncthreads();

    #pragma unroll 1
    for (int t = 0; t < NTILES; ++t) {
        const int kb = k_begin + t*KK;
        const char* bufP = smemB + (t & 1)*8192;
        char*       bufQ = smemB + ((t + 1) & 1)*8192;

        // ---- A fragments: per-lane global loads (coalesced from ws, no LDS) ----
        s16x8 arf[4], aif[4];
        if (PRE) {
            const char* tb = ws + (size_t)(kc*NTILES + t)*WS_TILE_B + lane*16;
            #pragma unroll
            for (int mi = 0; mi < 4; ++mi) {
                arf[mi] = *(const s16x8*)(tb +        (wm*4 + mi)*1024);
                aif[mi] = *(const s16x8*)(tb + 8192 + (wm*4 + mi)*1024);
            }
        } else {
            #pragma unroll
            for (int mi = 0; mi < 4; ++mi) {
                int row = wm*64 + mi*16 + frow;
                int k   = kb + kq*8;
                const float* pr_ = &cgr[(size_t)row*NG + k];
                const float* pi_ = &cgi[(size_t)row*NG + k];
                arf[mi] = pack8(*(const float4*)pr_, *(const float4*)(pr_+4));
                aif[mi] = pack8(*(const float4*)pi_, *(const float4*)(pi_+4));
            }
        }

        // ---- B fragments of tile t (written last iter, barrier'd) ----
        s16x8 bcf[2], bsf[2], bsnf[2];
        #pragma unroll
        for (int ni = 0; ni < 2; ++ni) {
            bcf[ni]  = *(const s16x8*)(bufP +        bOff + ni*1024);
            bsf[ni]  = *(const s16x8*)(bufP + 4096 + bOff + ni*1024);
            bsnf[ni] = bneg(bsf[ni]);
        }

        // ---- stage B(t+1) into bufQ (no dep on bufP reads -> overlaps MFMA) ----
        if (t + 1 < NTILES) stageB(kb + KK, bufQ);

        // ---- 16 MFMAs ----
        __builtin_amdgcn_s_setprio(1);
        #pragma unroll
        for (int mi = 0; mi < 4; ++mi)
            #pragma unroll
            for (int ni = 0; ni < 2; ++ni) {
                // Re += Ar*c + Ai*(-s) ; Im += Ar*s + Ai*c
                accRe[mi][ni] = __builtin_amdgcn_mfma_f32_16x16x32_bf16(arf[mi], bcf[ni],  accRe[mi][ni], 0, 0, 0);
                accRe[mi][ni] = __builtin_amdgcn_mfma_f32_16x16x32_bf16(aif[mi], bsnf[ni], accRe[mi][ni], 0, 0, 0);
                accIm[mi][ni] = __builtin_amdgcn_mfma_f32_16x16x32_bf16(arf[mi], bsf[ni],  accIm[mi][ni], 0, 0, 0);
                accIm[mi][ni] = __builtin_amdgcn_mfma_f32_16x16x32_bf16(aif[mi], bcf[ni],  accIm[mi][ni], 0, 0, 0);
            }
        __builtin_amdgcn_s_setprio(0);

        __syncthreads();   // one barrier/iter: q-writes visible; p-reads drained
    }

    // ---- e^{i k.r} table overlay on smemB; one sincos per thread ----
    float2* ekr = (float2*)smemB;   // [64][4]
    {
        int col = tid >> 2, kidx = tid & 3;
        int rg = r_base + col;
        float r0 = rpts[rg*3+0], r1 = rpts[rg*3+1], r2 = rpts[rg*3+2];
        float ang = (r0*kgrid[kidx*3+0] + r1*kgrid[kidx*3+1] + r2*kgrid[kidx*3+2])
                    * 0.15915494309189535f;
        float u = ang - floorf(ang);
        ekr[col*4+kidx] = make_float2(cos_rev(u), sin_rev(u));
    }
    __syncthreads();

    // ---- epilogue: rotate by exp(i k.r), scale, atomic-accumulate ----
    const bool write_imag = (out_size >= 2*NSKIN*NRPT);
    const float scale = scaleS;
    #pragma unroll
    for (int mi = 0; mi < 4; ++mi) {
        const int m0 = wm*64 + mi*16;
        const int kidx = (m0 >> 4) & 3;
        #pragma unroll
        for (int ni = 0; ni < 2; ++ni) {
            int col = wn*32 + ni*16 + frow;
            int rg = r_base + col;
            float2 e = ekr[col*4+kidx];
            float ck = e.x, sk = e.y;
            #pragma unroll
            for (int v = 0; v < 4; ++v) {
                int sg = m0 + kq*4 + v;
                float re = accRe[mi][ni][v];
                float im = accIm[mi][ni][v];
                float orr = (re*ck - im*sk) * scale;
                size_t lin = (size_t)sg * NRPT + rg;
                if (write_imag) {
                    float oi = (re*sk + im*ck) * scale;
                    size_t idx = lin * 2;
                    if (idx + 1 < (size_t)out_size) {
                        atomicAdd(&out[idx],   orr);
                        atomicAdd(&out[idx+1], oi);
                    }
                } else {
                    atomicAdd(&out[lin], orr);
                }
            }
        }
    }
}

extern "C" void kernel_launch(void* const* d_in, const int* in_sizes, int n_in,
                              void* d_out, int out_size, void* d_ws, size_t ws_size,
                              hipStream_t stream) {
    const float* Amat  = (const float*)d_in[0];
    const float* kgrid = (const float*)d_in[1];
    const float* cgr   = (const float*)d_in[2];
    const float* cgi   = (const float*)d_in[3];
    const float* rpts  = (const float*)d_in[4];
    float* out = (float*)d_out;

    hipMemsetAsync(d_out, 0, (size_t)out_size * sizeof(float), stream);

    const bool use_pre = (ws_size >= WS_NEED);
    dim3 grid(NKC * 128);   // kc = bid>>7, rb = bid&127 (3 dead bids per kc)
    if (use_pre) {
        bloch_prepass<<<dim3(NTOT*2*8*64/256), 256, 0, stream>>>(cgr, cgi, (char*)d_ws);
        bloch10<true><<<grid, TPB, 0, stream>>>(Amat, kgrid, cgr, cgi, rpts,
                                                (const char*)d_ws, out, out_size);
    } else {
        bloch10<false><<<grid, TPB, 0, stream>>>(Amat, kgrid, cgr, cgi, rpts,
                                                 nullptr, out, out_size);
    }
}

// Round 13
// 89.970 us; speedup vs baseline: 1.1656x; 1.0072x over previous
//
#include <hip/hip_runtime.h>

typedef __attribute__((ext_vector_type(4))) float f32x4;
typedef __attribute__((ext_vector_type(8))) short s16x8;

#define NG     8000
#define NRPT   8000
#define NSKIN  128
#define NT     64          // r-cols per block
#define KCH    800
#define NKC    10
#define NTILES 25          // 32-k tiles per chunk
#define NROUND 10          // 80-g staging rounds per chunk
#define NSLOT  6           // ring slots (192 g): live window <= 176 g -> disjoint
#define TPB    256
#define WS_TILE_B 16384    // per 32k-tile: Ar|Ai planes, 8KB each, fragment-ordered
#define WS_NEED   ((size_t)NKC*NTILES*WS_TILE_B)   // 4,096,000 B

__device__ __forceinline__ float sin_rev(float u){ float r; asm("v_sin_f32 %0, %1" : "=v"(r) : "v"(u)); return r; }
__device__ __forceinline__ float cos_rev(float u){ float r; asm("v_cos_f32 %0, %1" : "=v"(r) : "v"(u)); return r; }
__device__ __forceinline__ unsigned int cvt_pk(float lo, float hi){
    unsigned int r; asm("v_cvt_pk_bf16_f32 %0, %1, %2" : "=v"(r) : "v"(lo), "v"(hi)); return r;
}
__device__ __forceinline__ s16x8 bneg(s16x8 v){
    int4 u = *(int4*)&v;
    u.x ^= 0x80008000; u.y ^= 0x80008000; u.z ^= 0x80008000; u.w ^= 0x80008000;
    return *(s16x8*)&u;
}
__device__ __forceinline__ s16x8 pack8(float4 v0, float4 v1){
    union { s16x8 v; uint4 u; } r;
    r.u.x = cvt_pk(v0.x,v0.y); r.u.y = cvt_pk(v0.z,v0.w);
    r.u.z = cvt_pk(v1.x,v1.y); r.u.w = cvt_pk(v1.z,v1.w);
    return r.v;
}
// swizzled byte offset of 16B granule (row,kg) in a [64][32]-ushort plane (64B rows).
// kg' = kg ^ ((row>>1)&3): b128 writes and b128 frag reads (rows base+frow,
// kg=lane>>4) both land 8 lanes per 16B bank-group -> conflict-free.
__device__ __forceinline__ int swz(int row, int kg){
    return row*64 + ((kg ^ ((row>>1)&3))<<4);
}

// ---- pre-pass: cg fp32 -> bf16 in MFMA-fragment order ----
__global__ __launch_bounds__(256) void bloch_prepass(
    const float* __restrict__ cgr, const float* __restrict__ cgi,
    char* __restrict__ ws)
{
    int gid = blockIdx.x*256 + threadIdx.x;
    if (gid >= NKC*NTILES*2*8*64) return;
    int lane  = gid & 63;
    int rb8   = (gid >> 6) & 7;
    int plane = (gid >> 9) & 1;
    int tile  = gid >> 10;
    int row   = rb8*16 + (lane & 15);
    int k     = tile*32 + (lane >> 4)*8;
    const float* src = plane ? cgi : cgr;
    const float4 v0 = *(const float4*)&src[(size_t)row*NG + k];
    const float4 v1 = *(const float4*)&src[(size_t)row*NG + k + 4];
    uint4 p;
    p.x = cvt_pk(v0.x, v0.y); p.y = cvt_pk(v0.z, v0.w);
    p.z = cvt_pk(v1.x, v1.y); p.w = cvt_pk(v1.z, v1.w);
    *(uint4*)(ws + (size_t)gid*16) = p;
}

// (256,2): cap 256 VGPR -> zero spill risk (R8 lesson). 2 blocks/CU, LDS ~50KB.
template<bool PRE>
__global__ __launch_bounds__(TPB, 2) void bloch12(
    const float* __restrict__ Amat, const float* __restrict__ kgrid,
    const float* __restrict__ cgr,  const float* __restrict__ cgi,
    const float* __restrict__ rpts, const char* __restrict__ ws,
    float* __restrict__ out, int out_size)
{
    // B ring: 6 slots x (Bc 4K | Bs 4K) = 48KB (192 g).
    // Disjointness (ring pos mod 192): iter R reads [floor(5R/2)*32, 80R+80),
    // writes [80R+80, 80R+160); span <= 176 < 192 -> never intersect (verified
    // by enumeration R=0..9; the 5-slot/160-g version collided at odd R).
    __shared__ __align__(16) char smem[NSLOT*8192];
    __shared__ float fracS[NT][4];
    __shared__ float invAS[9];
    __shared__ float scaleS;

    const int tid = threadIdx.x;
    const int bid = blockIdx.x;
    const int kc  = bid >> 7;           // 0..9
    const int rb  = bid & 127;          // 0..127
    if (rb >= 125) return;              // uniform early-out
    const int r_base = rb * NT;

    if (tid == 0) {
        float a00=Amat[0],a01=Amat[1],a02=Amat[2];
        float a10=Amat[3],a11=Amat[4],a12=Amat[5];
        float a20=Amat[6],a21=Amat[7],a22=Amat[8];
        float c00 =  (a11*a22 - a12*a21);
        float c01 = -(a10*a22 - a12*a20);
        float c02 =  (a10*a21 - a11*a20);
        float det = a00*c00 + a01*c01 + a02*c02;
        float id  = 1.0f/det;
        invAS[0] =  c00*id;
        invAS[1] = -(a01*a22 - a02*a21)*id;
        invAS[2] =  (a01*a12 - a02*a11)*id;
        invAS[3] =  c01*id;
        invAS[4] =  (a00*a22 - a02*a20)*id;
        invAS[5] = -(a00*a12 - a02*a10)*id;
        invAS[6] =  c02*id;
        invAS[7] = -(a00*a21 - a01*a20)*id;
        invAS[8] =  (a00*a11 - a01*a10)*id;
        scaleS   = rsqrtf(fabsf(det));
    }
    __syncthreads();

    if (tid < NT) {
        int rg = r_base + tid;
        float r0 = rpts[rg*3+0], r1 = rpts[rg*3+1], r2 = rpts[rg*3+2];
        fracS[tid][0] = r0*invAS[0] + r1*invAS[3] + r2*invAS[6];
        fracS[tid][1] = r0*invAS[1] + r1*invAS[4] + r2*invAS[7];
        fracS[tid][2] = r0*invAS[2] + r1*invAS[5] + r2*invAS[8];
    }
    __syncthreads();

    f32x4 accRe[4][2], accIm[4][2];
    #pragma unroll
    for (int mi = 0; mi < 4; ++mi)
        #pragma unroll
        for (int ni = 0; ni < 2; ++ni) {
            accRe[mi][ni] = (f32x4){0.f,0.f,0.f,0.f};
            accIm[mi][ni] = (f32x4){0.f,0.f,0.f,0.f};
        }

    const int lane = tid & 63;
    const int wid  = tid >> 6;     // 0..3
    const int wm   = wid >> 1;     // M half (64 rows)
    const int wn   = wid & 1;      // N half (32 cols)
    const int frow = lane & 15;
    const int kq   = lane >> 4;
    const int bOff = swz(wn*32 + frow, kq);

    // staging: row = lane, run index = wid (wave-uniform store paths)
    const float f0r = fracS[lane][0], f1r = fracS[lane][1], f2r = fracS[lane][2];
    float u1 = f2r - floorf(f2r);
    const float w1c = cos_rev(u1), w1s = sin_rev(u1);        // e^{2pi i f2}
    float yd = -20.0f * f2r; yd -= floorf(yd);
    const float wdc = cos_rev(yd), wds = sin_rev(yd);
    const float w1wdc = w1c*wdc - w1s*wds;                   // w1 * e^{-2pi i 20 f2}
    const float w1wds = w1c*wds + w1s*wdc;

    // stage round R: 20-aligned run per thread -> no boundary selects;
    // only special step is j==10 (decade jump, compile-time).
    auto stageRing = [&](int R){
        int i12 = kc*40 + 4*R + wid;             // (kc*800 + R*80 + wid*20)/20
        int i1  = (i12 * 3277) >> 16;            // /20 exact for i12<16000
        int i2  = i12 - i1*20;
        float m1 = (float)(i1 - (i1 >= 10 ? 20 : 0));
        float m2 = (float)(i2 - (i2 >= 10 ? 20 : 0));
        float y0 = m1*f0r + m2*f1r; y0 -= floorf(y0);
        float cc = cos_rev(y0), cs = sin_rev(y0);            // phase j=0 (m3=0)
        unsigned int pkc[10], pks[10];
        #pragma unroll
        for (int jj = 0; jj < 10; ++jj) {
            float ac = cc, as_ = cs;
            { float nc = cc*w1c - cs*w1s, ns = cc*w1s + cs*w1c; cc=nc; cs=ns; } // -> j=2jj+1
            pkc[jj] = cvt_pk(ac, cc);
            pks[jj] = cvt_pk(as_, cs);
            if (jj < 9) {                                    // -> j=2jj+2
                if (jj == 4) { float nc = cc*w1wdc - cs*w1wds, ns = cc*w1wds + cs*w1wdc; cc=nc; cs=ns; }
                else         { float nc = cc*w1c  - cs*w1s,  ns = cc*w1s  + cs*w1c;  cc=nc; cs=ns; }
            }
        }
        // ring g-position of run start (multiple of 4): mod 192
        int gg = (80*R + wid*20) % 192;
        int gA = gg >> 3;                        // starting granule (0..23)
        // addr of ring granule g (mod 24), plane p (0=Bc,1=Bs)
        auto adr = [&](int g, int p)->char* {
            if (g >= 24) g -= 24;
            return smem + (g>>2)*8192 + p*4096 + swz(lane, g&3);
        };
        if ((gg & 7) == 0) {                     // run starts at granule boundary: 8,8,4
            *(uint4*)adr(gA,0)   = make_uint4(pkc[0],pkc[1],pkc[2],pkc[3]);
            *(uint4*)adr(gA+1,0) = make_uint4(pkc[4],pkc[5],pkc[6],pkc[7]);
            *(uint2*)adr(gA+2,0) = make_uint2(pkc[8],pkc[9]);
            *(uint4*)adr(gA,1)   = make_uint4(pks[0],pks[1],pks[2],pks[3]);
            *(uint4*)adr(gA+1,1) = make_uint4(pks[4],pks[5],pks[6],pks[7]);
            *(uint2*)adr(gA+2,1) = make_uint2(pks[8],pks[9]);
        } else {                                 // starts mid-granule (+4 g): 4,8,8
            *(uint2*)(adr(gA,0)+8) = make_uint2(pkc[0],pkc[1]);
            *(uint4*)adr(gA+1,0)   = make_uint4(pkc[2],pkc[3],pkc[4],pkc[5]);
            *(uint4*)adr(gA+2,0)   = make_uint4(pkc[6],pkc[7],pkc[8],pkc[9]);
            *(uint2*)(adr(gA,1)+8) = make_uint2(pks[0],pks[1]);
            *(uint4*)adr(gA+1,1)   = make_uint4(pks[2],pks[3],pks[4],pks[5]);
            *(uint4*)adr(gA+2,1)   = make_uint4(pks[6],pks[7],pks[8],pks[9]);
        }
    };

    s16x8 arfP[4], aifP[4];    // prefetched A fragments (current tile)
    auto loadA = [&](int t){
        if (PRE) {
            const char* tb = ws + (size_t)(kc*NTILES + t)*WS_TILE_B + lane*16;
            #pragma unroll
            for (int mi = 0; mi < 4; ++mi) {
                arfP[mi] = *(const s16x8*)(tb +        (wm*4 + mi)*1024);
                aifP[mi] = *(const s16x8*)(tb + 8192 + (wm*4 + mi)*1024);
            }
        } else {
            #pragma unroll
            for (int mi = 0; mi < 4; ++mi) {
                int row = wm*64 + mi*16 + frow;
                int k   = kc*KCH + t*32 + kq*8;
                const float* pr_ = &cgr[(size_t)row*NG + k];
                const float* pi_ = &cgi[(size_t)row*NG + k];
                arfP[mi] = pack8(*(const float4*)pr_, *(const float4*)(pr_+4));
                aifP[mi] = pack8(*(const float4*)pi_, *(const float4*)(pi_+4));
            }
        }
    };

    // prologue
    loadA(0);
    stageRing(0);
    __syncthreads();

    int tcur = 0, slot = 0;
    #pragma unroll 1
    for (int R = 0; R < NROUND; ++R) {
        if (R + 1 < NROUND) stageRing(R + 1);
        const int t_hi = (5*R + 5) >> 1;         // tiles available after round R
        #pragma unroll 1
        while (tcur < t_hi) {
            const char* base = smem + slot*8192;
            s16x8 bcf[2], bsf[2], bsnf[2];
            #pragma unroll
            for (int ni = 0; ni < 2; ++ni) {
                bcf[ni]  = *(const s16x8*)(base +        bOff + ni*1024);
                bsf[ni]  = *(const s16x8*)(base + 4096 + bOff + ni*1024);
                bsnf[ni] = bneg(bsf[ni]);
            }
            __builtin_amdgcn_s_setprio(1);
            #pragma unroll
            for (int mi = 0; mi < 4; ++mi)
                #pragma unroll
                for (int ni = 0; ni < 2; ++ni) {
                    accRe[mi][ni] = __builtin_amdgcn_mfma_f32_16x16x32_bf16(arfP[mi], bcf[ni],  accRe[mi][ni], 0, 0, 0);
                    accRe[mi][ni] = __builtin_amdgcn_mfma_f32_16x16x32_bf16(aifP[mi], bsnf[ni], accRe[mi][ni], 0, 0, 0);
                    accIm[mi][ni] = __builtin_amdgcn_mfma_f32_16x16x32_bf16(arfP[mi], bsf[ni],  accIm[mi][ni], 0, 0, 0);
                    accIm[mi][ni] = __builtin_amdgcn_mfma_f32_16x16x32_bf16(aifP[mi], bcf[ni],  accIm[mi][ni], 0, 0, 0);
                }
            __builtin_amdgcn_s_setprio(0);
            ++tcur;
            if (tcur < NTILES) loadA(tcur);      // prefetch next tile's A
            ++slot; if (slot == NSLOT) slot = 0;
        }
        __syncthreads();                         // round R+1 visible; ring reuse safe
    }

    // ---- e^{i k.r} table overlay on smem; one sincos per thread ----
    float2* ekr = (float2*)smem;   // [64][4]
    {
        int col = tid >> 2, kidx = tid & 3;
        int rg = r_base + col;
        float r0 = rpts[rg*3+0], r1 = rpts[rg*3+1], r2 = rpts[rg*3+2];
        float ang = (r0*kgrid[kidx*3+0] + r1*kgrid[kidx*3+1] + r2*kgrid[kidx*3+2])
                    * 0.15915494309189535f;
        float u = ang - floorf(ang);
        ekr[col*4+kidx] = make_float2(cos_rev(u), sin_rev(u));
    }
    __syncthreads();

    // ---- epilogue: rotate by exp(i k.r), scale, atomic-accumulate ----
    const bool write_imag = (out_size >= 2*NSKIN*NRPT);
    const float scale = scaleS;
    #pragma unroll
    for (int mi = 0; mi < 4; ++mi) {
        const int m0 = wm*64 + mi*16;
        const int kidx = (m0 >> 4) & 3;
        #pragma unroll
        for (int ni = 0; ni < 2; ++ni) {
            int col = wn*32 + ni*16 + frow;
            int rg = r_base + col;
            float2 e = ekr[col*4+kidx];
            float ck = e.x, sk = e.y;
            #pragma unroll
            for (int v = 0; v < 4; ++v) {
                int sg = m0 + kq*4 + v;
                float re = accRe[mi][ni][v];
                float im = accIm[mi][ni][v];
                float orr = (re*ck - im*sk) * scale;
                size_t lin = (size_t)sg * NRPT + rg;
                if (write_imag) {
                    float oi = (re*sk + im*ck) * scale;
                    size_t idx = lin * 2;
                    if (idx + 1 < (size_t)out_size) {
                        atomicAdd(&out[idx],   orr);
                        atomicAdd(&out[idx+1], oi);
                    }
                } else {
                    atomicAdd(&out[lin], orr);
                }
            }
        }
    }
}

extern "C" void kernel_launch(void* const* d_in, const int* in_sizes, int n_in,
                              void* d_out, int out_size, void* d_ws, size_t ws_size,
                              hipStream_t stream) {
    const float* Amat  = (const float*)d_in[0];
    const float* kgrid = (const float*)d_in[1];
    const float* cgr   = (const float*)d_in[2];
    const float* cgi   = (const float*)d_in[3];
    const float* rpts  = (const float*)d_in[4];
    float* out = (float*)d_out;

    hipMemsetAsync(d_out, 0, (size_t)out_size * sizeof(float), stream);

    const bool use_pre = (ws_size >= WS_NEED);
    dim3 grid(NKC * 128);   // kc = bid>>7, rb = bid&127 (3 dead bids per kc)
    if (use_pre) {
        bloch_prepass<<<dim3(NKC*NTILES*2*8*64/256), 256, 0, stream>>>(cgr, cgi, (char*)d_ws);
        bloch12<true><<<grid, TPB, 0, stream>>>(Amat, kgrid, cgr, cgi, rpts,
                                                (const char*)d_ws, out, out_size);
    } else {
        bloch12<false><<<grid, TPB, 0, stream>>>(Amat, kgrid, cgr, cgi, rpts,
                                                 nullptr, out, out_size);
    }
}